// Round 2
// baseline (1135.810 us; speedup 1.0000x reference)
//
#include <hip/hip_runtime.h>
#include <hip/hip_bf16.h>

typedef __hip_bfloat16 bf16;

#define NTOK 512
#define DIM 512
#define CCH 256
#define IMH 128
#define IMW 128
#define NP 36
#define TOTC 66832
#define CM_SZ 65536
#define TCHUNK 256

__device__ __forceinline__ float b2f(bf16 x) { return __bfloat162float(x); }
__device__ __forceinline__ bf16 f2b(float x) { return __float2bfloat16(x); }
__device__ __forceinline__ float gelu_f(float x) {
  return 0.5f * x * (1.0f + erff(x * 0.7071067811865476f));
}

// ---------------- img_feat (B,C,H,W) f32 -> (B,H,W,C) bf16 ----------------
__global__ __launch_bounds__(256) void k_transpose(const float* __restrict__ img,
                                                   bf16* __restrict__ imgT) {
  int b = blockIdx.y;
  int hw0 = blockIdx.x * 32;
  __shared__ float tile[256][33];
  int t = threadIdx.x;
  int hw = t & 31, c0 = t >> 5;
#pragma unroll 8
  for (int i = 0; i < 32; ++i) {
    int c = c0 + 8 * i;
    tile[c][hw] = img[((size_t)(b * 256 + c) << 14) + hw0 + hw];
  }
  __syncthreads();
#pragma unroll 8
  for (int i = 0; i < 32; ++i) {
    imgT[(((size_t)b << 14) + hw0 + i) * 256 + t] = f2b(tile[t][i]);
  }
}

// ---------------- per-token prep ----------------
__global__ __launch_bounds__(256) void k_prep(
    const float* __restrict__ te, const float* __restrict__ roi,
    const float* __restrict__ g_off, const float* __restrict__ b_off,
    const float* __restrict__ w_off, const float* __restrict__ off_bias,
    const float* __restrict__ g_pg, const float* __restrict__ b_pg,
    const float* __restrict__ w_pg1, const float* __restrict__ b_pg1,
    float* __restrict__ t_out, int* __restrict__ meta_i, float* __restrict__ meta_w) {
  int tok = blockIdx.x;
  int t = threadIdx.x, lane = t & 63, w = t >> 6;
  __shared__ float xo[512], xq[512], offb[72], red[4], wsum[4];
  size_t base = (size_t)tok * 512;
  float a0 = te[base + t];
  float a1 = te[base + t + 256];
  float s = a0 + a1;
#pragma unroll
  for (int o = 32; o; o >>= 1) s += __shfl_xor(s, o);
  if (lane == 0) wsum[w] = s;
  __syncthreads();
  float mean = (wsum[0] + wsum[1] + wsum[2] + wsum[3]) * (1.0f / 512.0f);
  float d0 = a0 - mean, d1 = a1 - mean;
  float ss = d0 * d0 + d1 * d1;
#pragma unroll
  for (int o = 32; o; o >>= 1) ss += __shfl_xor(ss, o);
  __syncthreads();
  if (lane == 0) wsum[w] = ss;
  __syncthreads();
  float var = (wsum[0] + wsum[1] + wsum[2] + wsum[3]) * (1.0f / 512.0f);
  float rstd = rsqrtf(var + 1e-5f);
  xo[t] = d0 * rstd * g_off[t] + b_off[t];
  xo[t + 256] = d1 * rstd * g_off[t + 256] + b_off[t + 256];
  xq[t] = d0 * rstd * g_pg[t] + b_pg[t];
  xq[t + 256] = d1 * rstd * g_pg[t + 256] + b_pg[t + 256];
  __syncthreads();
  if (t < 128) {
    float acc = b_pg1[t];
    for (int d = 0; d < 512; ++d) acc = fmaf(xq[d], w_pg1[d * 128 + t], acc);
    t_out[(size_t)tok * 128 + t] = acc;
  } else if (t < 200) {
    int j = t - 128;
    float acc = off_bias[j];
    for (int d = 0; d < 512; ++d) acc = fmaf(xo[d], w_off[d * 72 + j], acc);
    offb[j] = acc;
  }
  __syncthreads();
  if (t < 2) {
    float mu = 0.f;
    for (int p = 0; p < 36; ++p) mu += offb[p * 2 + t];
    mu *= (1.0f / 36.0f);
    float s2 = 0.f;
    for (int p = 0; p < 36; ++p) { float dd = offb[p * 2 + t] - mu; s2 += dd * dd; }
    float sd = sqrtf(s2 * (1.0f / 35.0f)) + 1e-5f;  // ddof=1, then +1e-5
    red[t] = mu;
    red[2 + t] = 1.0f / (3.0f * sd);
  }
  __syncthreads();
  if (t < 36) {
    int p = t;
    float r0 = roi[tok * 4 + 0], r1 = roi[tok * 4 + 1];
    float r2 = roi[tok * 4 + 2], r3 = roi[tok * 4 + 3];
    float cx = (r0 + r2) * 0.5f, cy = (r1 + r3) * 0.5f;
    float bw = r2 - r0, bh = r3 - r1;
    float ox = (offb[p * 2 + 0] - red[0]) * red[2];
    float oy = (offb[p * 2 + 1] - red[1]) * red[3];
    float fx = (cx + ox * bw) * 128.0f - 0.5f;
    float fy = (cy + oy * bh) * 128.0f - 0.5f;
    float x0f = floorf(fx), y0f = floorf(fy);
    float wx = fx - x0f, wy = fy - y0f;
    int x0 = min(max((int)x0f, 0), 127);
    int x1 = min(max((int)x0f + 1, 0), 127);
    int y0 = min(max((int)y0f, 0), 127);
    int y1 = min(max((int)y0f + 1, 0), 127);
    int ibase = (tok >> 6) * 16384;
    int mi = (tok * 36 + p) * 4;
    meta_i[mi + 0] = (ibase + y0 * 128 + x0) * 256;
    meta_i[mi + 1] = (ibase + y0 * 128 + x1) * 256;
    meta_i[mi + 2] = (ibase + y1 * 128 + x0) * 256;
    meta_i[mi + 3] = (ibase + y1 * 128 + x1) * 256;
    meta_w[mi + 0] = (1.f - wx) * (1.f - wy);
    meta_w[mi + 1] = wx * (1.f - wy);
    meta_w[mi + 2] = (1.f - wx) * wy;
    meta_w[mi + 3] = wx * wy;
  }
}

// ---------------- params_chunk = t(TCHUNKx128) @ w_pg2 + b_pg2, bf16 out ----------------
__global__ __launch_bounds__(256) void k_pg2(const float* __restrict__ tbuf,
                                             const float* __restrict__ w2,
                                             const float* __restrict__ b2,
                                             bf16* __restrict__ params) {
  int col = blockIdx.x * 256 + threadIdx.x;
  if (col >= TOTC) return;
  int tk0 = blockIdx.y * 16;
  const float* tp = tbuf + (size_t)tk0 * 128;  // uniform -> scalar loads
  float acc[16];
  float bv = b2[col];
#pragma unroll
  for (int i = 0; i < 16; ++i) acc[i] = bv;
  for (int k = 0; k < 128; ++k) {
    float wv = w2[(size_t)k * TOTC + col];
#pragma unroll
    for (int i = 0; i < 16; ++i) acc[i] = fmaf(tp[i * 128 + k], wv, acc[i]);
  }
#pragma unroll
  for (int i = 0; i < 16; ++i) params[(size_t)(tk0 + i) * TOTC + col] = f2b(acc[i]);
}

// ---------------- bilinear gather ----------------
__global__ __launch_bounds__(256) void k_sample(const bf16* __restrict__ imgT,
                                                const int* __restrict__ meta_i,
                                                const float* __restrict__ meta_w,
                                                float* __restrict__ S) {
  int tok = blockIdx.x, t = threadIdx.x;
  for (int p = 0; p < 36; ++p) {
    int mi = (tok * 36 + p) * 4;
    int o00 = meta_i[mi + 0], o01 = meta_i[mi + 1], o10 = meta_i[mi + 2], o11 = meta_i[mi + 3];
    float w00 = meta_w[mi + 0], w01 = meta_w[mi + 1], w10 = meta_w[mi + 2], w11 = meta_w[mi + 3];
    float v = w00 * b2f(imgT[o00 + t]) + w01 * b2f(imgT[o01 + t]) +
              w10 * b2f(imgT[o10 + t]) + w11 * b2f(imgT[o11 + t]);
    S[((size_t)tok * 36 + p) * 256 + t] = v;
  }
}

// ---------------- fused mixing ----------------
__global__ __launch_bounds__(256) void k_mix(const bf16* __restrict__ params,
                                             const float* __restrict__ S, int t0,
                                             const float* __restrict__ m_beta,
                                             const float* __restrict__ s_beta,
                                             bf16* __restrict__ h2) {
  int ltok = blockIdx.x;
  int tok = t0 + ltok;
  int d = threadIdx.x;
  const bf16* cm = params + (size_t)ltok * TOTC;
  const bf16* sm = cm + CM_SZ;
  const float* Sp = S + (size_t)tok * 36 * 256;
  float acc[36];
  float mb = m_beta[d];
#pragma unroll
  for (int p = 0; p < 36; ++p) acc[p] = mb;
  for (int cb = 0; cb < 256; cb += 32) {
    float cmv[32];
#pragma unroll
    for (int i = 0; i < 32; ++i) cmv[i] = b2f(cm[(size_t)(cb + i) * 256 + d]);
#pragma unroll
    for (int p = 0; p < 36; ++p) {
      const float* sp = Sp + p * 256 + cb;
#pragma unroll
      for (int i = 0; i < 32; ++i) acc[p] = fmaf(sp[i], cmv[i], acc[p]);
    }
  }
#pragma unroll
  for (int p = 0; p < 36; ++p) acc[p] = gelu_f(acc[p]);
  for (int q = 0; q < 36; ++q) {
    float a = s_beta[q];
#pragma unroll
    for (int p = 0; p < 36; ++p) a = fmaf(b2f(sm[q * 36 + p]), acc[p], a);
    h2[(size_t)tok * 9216 + q * 256 + d] = f2b(gelu_f(a));
  }
}

// ---------------- generic tiled GEMM: A bf16, B f32 ----------------
__global__ __launch_bounds__(256) void k_gemm(const bf16* __restrict__ A,
                                              const float* __restrict__ Bm,
                                              float* __restrict__ part,
                                              int M, int N, int K) {
  int nb = blockIdx.x, mb = blockIdx.y, ks = blockIdx.z;
  int kchunk = K / gridDim.z;
  int k0 = ks * kchunk;
  __shared__ __attribute__((aligned(16))) float As[32][68];
  __shared__ __attribute__((aligned(16))) float Bs[32][68];
  int t = threadIdx.x;
  int tm = t >> 4, tn = t & 15;
  float acc[4][4] = {};
  for (int kt = 0; kt < kchunk; kt += 32) {
#pragma unroll
    for (int i = 0; i < 8; ++i) {
      int idx = t + i * 256;
      int m = idx >> 5, kk = idx & 31;
      As[kk][m] = b2f(A[(size_t)(mb * 64 + m) * K + k0 + kt + kk]);
    }
#pragma unroll
    for (int i = 0; i < 8; ++i) {
      int idx = t + i * 256;
      int kk = idx >> 6, n = idx & 63;
      Bs[kk][n] = Bm[(size_t)(k0 + kt + kk) * N + nb * 64 + n];
    }
    __syncthreads();
#pragma unroll
    for (int kk = 0; kk < 32; ++kk) {
      float av[4], bv[4];
#pragma unroll
      for (int i = 0; i < 4; ++i) av[i] = As[kk][tm * 4 + i];
#pragma unroll
      for (int j = 0; j < 4; ++j) bv[j] = Bs[kk][tn * 4 + j];
#pragma unroll
      for (int i = 0; i < 4; ++i)
#pragma unroll
        for (int j = 0; j < 4; ++j) acc[i][j] = fmaf(av[i], bv[j], acc[i][j]);
    }
    __syncthreads();
  }
#pragma unroll
  for (int i = 0; i < 4; ++i) {
    size_t row = (size_t)ks * M * N + (size_t)(mb * 64 + tm * 4 + i) * N + nb * 64 + tn * 4;
#pragma unroll
    for (int j = 0; j < 4; ++j) part[row + j] = acc[i][j];
  }
}

// ---------------- epilogue ----------------
__global__ __launch_bounds__(256) void k_epi(const float* __restrict__ part, int S_,
                                             int MN, int N, const float* __restrict__ bias,
                                             const float* __restrict__ resf, int do_gelu,
                                             float* __restrict__ outf, bf16* __restrict__ outh) {
  int idx = blockIdx.x * 256 + threadIdx.x;
  if (idx >= MN) return;
  int n = idx % N;
  float a = 0.f;
  for (int s = 0; s < S_; ++s) a += part[(size_t)s * MN + idx];
  a += bias[n];
  if (resf) a += resf[idx];
  if (do_gelu) a = gelu_f(a);
  if (outf) outf[idx] = a;
  if (outh) outh[idx] = f2b(a);
}

// ---------------- LayerNorm: f32 in -> bf16 out ----------------
__global__ __launch_bounds__(256) void k_ln(const float* __restrict__ x,
                                            const float* __restrict__ g,
                                            const float* __restrict__ b,
                                            bf16* __restrict__ out) {
  int tok = blockIdx.x, t = threadIdx.x, lane = t & 63, w = t >> 6;
  __shared__ float wsum[4];
  size_t base = (size_t)tok * 512;
  float a0 = x[base + t], a1 = x[base + t + 256];
  float s = a0 + a1;
#pragma unroll
  for (int o = 32; o; o >>= 1) s += __shfl_xor(s, o);
  if (lane == 0) wsum[w] = s;
  __syncthreads();
  float mean = (wsum[0] + wsum[1] + wsum[2] + wsum[3]) * (1.0f / 512.0f);
  float d0 = a0 - mean, d1 = a1 - mean;
  float ss = d0 * d0 + d1 * d1;
#pragma unroll
  for (int o = 32; o; o >>= 1) ss += __shfl_xor(ss, o);
  __syncthreads();
  if (lane == 0) wsum[w] = ss;
  __syncthreads();
  float var = (wsum[0] + wsum[1] + wsum[2] + wsum[3]) * (1.0f / 512.0f);
  float rstd = rsqrtf(var + 1e-5f);
  out[base + t] = f2b(d0 * rstd * g[t] + b[t]);
  out[base + t + 256] = f2b(d1 * rstd * g[t + 256] + b[t + 256]);
}

// ---------------- attention ----------------
__global__ __launch_bounds__(256) void k_attn(const float* __restrict__ qkvf,
                                              bf16* __restrict__ obuf) {
  int b = blockIdx.x >> 3, h = blockIdx.x & 7;
  __shared__ float kT[64][65];
  __shared__ float vT[64][65];
  __shared__ float att[64][65];
  int t = threadIdx.x, lane = t & 63, w = t >> 6;
#pragma unroll
  for (int i = 0; i < 16; ++i) {
    int idx = t + i * 256;
    int j = idx >> 6, d = idx & 63;
    size_t tb = (size_t)(b * 64 + j) * 1536 + h * 64 + d;
    kT[j][d] = qkvf[tb + 512];
    vT[j][d] = qkvf[tb + 1024];
  }
  __syncthreads();
#pragma unroll 4
  for (int m = 0; m < 16; ++m) {
    int i = w * 16 + m;
    const float* qrow = &qkvf[(size_t)(b * 64 + i) * 1536 + h * 64];
    float s = 0.f;
    for (int d = 0; d < 64; ++d) s = fmaf(qrow[d], kT[lane][d], s);
    s *= 0.125f;
    float mx = s;
#pragma unroll
    for (int o = 32; o; o >>= 1) mx = fmaxf(mx, __shfl_xor(mx, o));
    float e = expf(s - mx);
    float sum = e;
#pragma unroll
    for (int o = 32; o; o >>= 1) sum += __shfl_xor(sum, o);
    att[i][lane] = e / sum;
  }
  __syncthreads();
#pragma unroll 4
  for (int m = 0; m < 16; ++m) {
    int i = w * 16 + m;
    float o = 0.f;
    for (int j = 0; j < 64; ++j) o = fmaf(att[i][j], vT[j][lane], o);
    obuf[(size_t)(b * 64 + i) * 512 + h * 64 + lane] = f2b(o);
  }
}

extern "C" void kernel_launch(void* const* d_in, const int* in_sizes, int n_in,
                              void* d_out, int out_size, void* d_ws, size_t ws_size,
                              hipStream_t stream) {
  const float* te = (const float*)d_in[0];
  const float* roi = (const float*)d_in[1];
  const float* img = (const float*)d_in[2];
  const float* ln_off_g = (const float*)d_in[3];
  const float* ln_off_b = (const float*)d_in[4];
  const float* w_off = (const float*)d_in[5];
  const float* off_bias = (const float*)d_in[6];
  const float* ln_pg_g = (const float*)d_in[7];
  const float* ln_pg_b = (const float*)d_in[8];
  const float* w_pg1 = (const float*)d_in[9];
  const float* b_pg1 = (const float*)d_in[10];
  const float* w_pg2 = (const float*)d_in[11];
  const float* b_pg2 = (const float*)d_in[12];
  const float* m_beta = (const float*)d_in[13];
  const float* s_beta = (const float*)d_in[14];
  const float* w_out = (const float*)d_in[15];
  const float* b_out = (const float*)d_in[16];
  const float* ln1_g = (const float*)d_in[17];
  const float* ln1_b = (const float*)d_in[18];
  const float* w_qkv = (const float*)d_in[19];
  const float* b_qkv = (const float*)d_in[20];
  const float* w_proj = (const float*)d_in[21];
  const float* b_proj = (const float*)d_in[22];
  const float* ln2_g = (const float*)d_in[23];
  const float* ln2_b = (const float*)d_in[24];
  const float* w_fc1 = (const float*)d_in[25];
  const float* b_fc1 = (const float*)d_in[26];
  const float* w_fc2 = (const float*)d_in[27];
  const float* b_fc2 = (const float*)d_in[28];

  char* ws = (char*)d_ws;
  // Region A: imgT (dead after k_sample), overlaid by post-sample buffers
  bf16* imgT = (bf16*)ws;                    // 67,108,864 B
  char* ov = ws;
  bf16* h2 = (bf16*)ov; ov += 9437184;
  float* part = (float*)ov; ov += 8388608;
  float* x1 = (float*)ov; ov += 1048576;
  float* xa = (float*)ov; ov += 1048576;
  float* qkvf = (float*)ov; ov += 3145728;
  bf16* ln1buf = (bf16*)ov; ov += 524288;
  bf16* ln2buf = (bf16*)ov; ov += 524288;
  bf16* obuf = (bf16*)ov; ov += 524288;
  bf16* hfc = (bf16*)ov; ov += 2097152;
  // Region B: persistent
  char* tail = ws + 67108864;
  float* Sbuf = (float*)tail; tail += 18874368;
  float* tbuf = (float*)tail; tail += 262144;
  int* meta_i = (int*)tail; tail += 294912;
  float* meta_w = (float*)tail; tail += 294912;
  bf16* pchunk = (bf16*)tail; tail += (size_t)TCHUNK * TOTC * 2;
  (void)ws_size;

  k_transpose<<<dim3(512, 8), 256, 0, stream>>>(img, imgT);
  k_prep<<<512, 256, 0, stream>>>(te, roi, ln_off_g, ln_off_b, w_off, off_bias,
                                  ln_pg_g, ln_pg_b, w_pg1, b_pg1, tbuf, meta_i, meta_w);
  k_sample<<<512, 256, 0, stream>>>(imgT, meta_i, meta_w, Sbuf);
  for (int c = 0; c < NTOK / TCHUNK; ++c) {
    int t0 = c * TCHUNK;
    k_pg2<<<dim3(262, TCHUNK / 16), 256, 0, stream>>>(tbuf + (size_t)t0 * 128, w_pg2, b_pg2, pchunk);
    k_mix<<<TCHUNK, 256, 0, stream>>>(pchunk, Sbuf, t0, m_beta, s_beta, h2);
  }

  k_gemm<<<dim3(8, 8, 8), 256, 0, stream>>>(h2, w_out, part, 512, 512, 9216);
  k_epi<<<1024, 256, 0, stream>>>(part, 8, 512 * 512, 512, b_out, te, 0, x1, nullptr);

  k_ln<<<512, 256, 0, stream>>>(x1, ln1_g, ln1_b, ln1buf);
  k_gemm<<<dim3(24, 8, 2), 256, 0, stream>>>(ln1buf, w_qkv, part, 512, 1536, 512);
  k_epi<<<3072, 256, 0, stream>>>(part, 2, 512 * 1536, 1536, b_qkv, nullptr, 0, qkvf, nullptr);
  k_attn<<<64, 256, 0, stream>>>(qkvf, obuf);
  k_gemm<<<dim3(8, 8, 4), 256, 0, stream>>>(obuf, w_proj, part, 512, 512, 512);
  k_epi<<<1024, 256, 0, stream>>>(part, 4, 512 * 512, 512, b_proj, x1, 0, xa, nullptr);

  k_ln<<<512, 256, 0, stream>>>(xa, ln2_g, ln2_b, ln2buf);
  k_gemm<<<dim3(32, 8, 2), 256, 0, stream>>>(ln2buf, w_fc1, part, 512, 2048, 512);
  k_epi<<<4096, 256, 0, stream>>>(part, 2, 512 * 2048, 2048, b_fc1, nullptr, 1, nullptr, hfc);
  k_gemm<<<dim3(8, 8, 4), 256, 0, stream>>>(hfc, w_fc2, part, 512, 512, 2048);
  k_epi<<<1024, 256, 0, stream>>>(part, 4, 512 * 512, 512, b_fc2, xa, 0, (float*)d_out, nullptr);
}

// Round 3
// 659.640 us; speedup vs baseline: 1.7219x; 1.7219x over previous
//
#include <hip/hip_runtime.h>
#include <hip/hip_bf16.h>

typedef __hip_bfloat16 bf16;
typedef __attribute__((ext_vector_type(8))) short short8;
typedef __attribute__((ext_vector_type(4))) float f32x4;

#define NTOK 512
#define TOTC 66832
#define CM_SZ 65536
#define TCHUNK 256

__device__ __forceinline__ float b2f(bf16 x) { return __bfloat162float(x); }
__device__ __forceinline__ bf16 f2b(float x) { return __float2bfloat16(x); }
__device__ __forceinline__ float gelu_f(float x) {
  return 0.5f * x * (1.0f + erff(x * 0.7071067811865476f));
}
__device__ __forceinline__ f32x4 mfma16(short8 a, short8 b, f32x4 c) {
  return __builtin_amdgcn_mfma_f32_16x16x32_bf16(a, b, c, 0, 0, 0);
}

// ---------------- img_feat (B,C,H,W) f32 -> (B,H,W,C) bf16 ----------------
__global__ __launch_bounds__(256) void k_transpose(const float* __restrict__ img,
                                                   bf16* __restrict__ imgT) {
  int b = blockIdx.y;
  int hw0 = blockIdx.x * 32;
  __shared__ float tile[256][33];
  int t = threadIdx.x;
  int hw = t & 31, c0 = t >> 5;
#pragma unroll 8
  for (int i = 0; i < 32; ++i) {
    int c = c0 + 8 * i;
    tile[c][hw] = img[((size_t)(b * 256 + c) << 14) + hw0 + hw];
  }
  __syncthreads();
#pragma unroll 8
  for (int i = 0; i < 32; ++i) {
    imgT[(((size_t)b << 14) + hw0 + i) * 256 + t] = f2b(tile[t][i]);
  }
}

// ---------------- per-token prep ----------------
__global__ __launch_bounds__(256) void k_prep(
    const float* __restrict__ te, const float* __restrict__ roi,
    const float* __restrict__ g_off, const float* __restrict__ b_off,
    const float* __restrict__ w_off, const float* __restrict__ off_bias,
    const float* __restrict__ g_pg, const float* __restrict__ b_pg,
    const float* __restrict__ w_pg1, const float* __restrict__ b_pg1,
    bf16* __restrict__ t_out, int* __restrict__ meta_i, float* __restrict__ meta_w) {
  int tok = blockIdx.x;
  int t = threadIdx.x, lane = t & 63, w = t >> 6;
  __shared__ float xo[512], xq[512], offb[72], red[4], wsum[4];
  size_t base = (size_t)tok * 512;
  float a0 = te[base + t];
  float a1 = te[base + t + 256];
  float s = a0 + a1;
#pragma unroll
  for (int o = 32; o; o >>= 1) s += __shfl_xor(s, o);
  if (lane == 0) wsum[w] = s;
  __syncthreads();
  float mean = (wsum[0] + wsum[1] + wsum[2] + wsum[3]) * (1.0f / 512.0f);
  float d0 = a0 - mean, d1 = a1 - mean;
  float ss = d0 * d0 + d1 * d1;
#pragma unroll
  for (int o = 32; o; o >>= 1) ss += __shfl_xor(ss, o);
  __syncthreads();
  if (lane == 0) wsum[w] = ss;
  __syncthreads();
  float var = (wsum[0] + wsum[1] + wsum[2] + wsum[3]) * (1.0f / 512.0f);
  float rstd = rsqrtf(var + 1e-5f);
  xo[t] = d0 * rstd * g_off[t] + b_off[t];
  xo[t + 256] = d1 * rstd * g_off[t + 256] + b_off[t + 256];
  xq[t] = d0 * rstd * g_pg[t] + b_pg[t];
  xq[t + 256] = d1 * rstd * g_pg[t + 256] + b_pg[t + 256];
  __syncthreads();
  if (t < 128) {
    float acc = b_pg1[t];
    for (int d = 0; d < 512; ++d) acc = fmaf(xq[d], w_pg1[d * 128 + t], acc);
    t_out[(size_t)tok * 128 + t] = f2b(acc);
  } else if (t < 200) {
    int j = t - 128;
    float acc = off_bias[j];
    for (int d = 0; d < 512; ++d) acc = fmaf(xo[d], w_off[d * 72 + j], acc);
    offb[j] = acc;
  }
  __syncthreads();
  if (t < 2) {
    float mu = 0.f;
    for (int p = 0; p < 36; ++p) mu += offb[p * 2 + t];
    mu *= (1.0f / 36.0f);
    float s2 = 0.f;
    for (int p = 0; p < 36; ++p) { float dd = offb[p * 2 + t] - mu; s2 += dd * dd; }
    float sd = sqrtf(s2 * (1.0f / 35.0f)) + 1e-5f;  // ddof=1, then +1e-5
    red[t] = mu;
    red[2 + t] = 1.0f / (3.0f * sd);
  }
  __syncthreads();
  if (t < 36) {
    int p = t;
    float r0 = roi[tok * 4 + 0], r1 = roi[tok * 4 + 1];
    float r2 = roi[tok * 4 + 2], r3 = roi[tok * 4 + 3];
    float cx = (r0 + r2) * 0.5f, cy = (r1 + r3) * 0.5f;
    float bw = r2 - r0, bh = r3 - r1;
    float ox = (offb[p * 2 + 0] - red[0]) * red[2];
    float oy = (offb[p * 2 + 1] - red[1]) * red[3];
    float fx = (cx + ox * bw) * 128.0f - 0.5f;
    float fy = (cy + oy * bh) * 128.0f - 0.5f;
    float x0f = floorf(fx), y0f = floorf(fy);
    float wx = fx - x0f, wy = fy - y0f;
    int x0 = min(max((int)x0f, 0), 127);
    int x1 = min(max((int)x0f + 1, 0), 127);
    int y0 = min(max((int)y0f, 0), 127);
    int y1 = min(max((int)y0f + 1, 0), 127);
    int ibase = (tok >> 6) * 16384;
    int mi = (tok * 36 + p) * 4;
    meta_i[mi + 0] = (ibase + y0 * 128 + x0) * 256;
    meta_i[mi + 1] = (ibase + y0 * 128 + x1) * 256;
    meta_i[mi + 2] = (ibase + y1 * 128 + x0) * 256;
    meta_i[mi + 3] = (ibase + y1 * 128 + x1) * 256;
    meta_w[mi + 0] = (1.f - wx) * (1.f - wy);
    meta_w[mi + 1] = wx * (1.f - wy);
    meta_w[mi + 2] = (1.f - wx) * wy;
    meta_w[mi + 3] = wx * wy;
  }
}

// ---------------- bilinear gather -> S bf16 ----------------
__global__ __launch_bounds__(256) void k_sample(const bf16* __restrict__ imgT,
                                                const int* __restrict__ meta_i,
                                                const float* __restrict__ meta_w,
                                                bf16* __restrict__ S) {
  int tok = blockIdx.x, t = threadIdx.x;
  for (int p = 0; p < 36; ++p) {
    int mi = (tok * 36 + p) * 4;
    int o00 = meta_i[mi + 0], o01 = meta_i[mi + 1], o10 = meta_i[mi + 2], o11 = meta_i[mi + 3];
    float w00 = meta_w[mi + 0], w01 = meta_w[mi + 1], w10 = meta_w[mi + 2], w11 = meta_w[mi + 3];
    float v = w00 * b2f(imgT[o00 + t]) + w01 * b2f(imgT[o01 + t]) +
              w10 * b2f(imgT[o10 + t]) + w11 * b2f(imgT[o11 + t]);
    S[((size_t)tok * 36 + p) * 256 + t] = f2b(v);
  }
}

// ---------------- phase A: pchunk = tb16(256x128) @ w_pg2(128xTOTC) + b_pg2 ----------------
// MFMA 16x16x32. Block: 64 cols; 4 waves x 64 rows each. A direct from global (L2-hot).
__global__ __launch_bounds__(256) void k_pg2_mfma(const bf16* __restrict__ tb16,
                                                  const float* __restrict__ w2,
                                                  const float* __restrict__ b2,
                                                  bf16* __restrict__ pchunk) {
  int n0 = blockIdx.x * 64;
  int t = threadIdx.x, lane = t & 63, w = t >> 6;
  int quad = lane >> 4, l16 = lane & 15;
  __shared__ bf16 BsT[64][136];  // [n][k], k-pad 128->136 (2-way bank alias only)
  {
    int nl = (t & 15) * 4, kk = t >> 4;
#pragma unroll
    for (int pass = 0; pass < 8; ++pass) {
      int k = kk + pass * 16;
      int n = n0 + nl;
      int nc = (n + 3 < TOTC) ? n : (TOTC - 4);  // clamp to stay in-bounds; masked later
      const float4 v = *(const float4*)(w2 + (size_t)k * TOTC + nc);
      BsT[nl + 0][k] = f2b(v.x);
      BsT[nl + 1][k] = f2b(v.y);
      BsT[nl + 2][k] = f2b(v.z);
      BsT[nl + 3][k] = f2b(v.w);
    }
  }
  __syncthreads();
  f32x4 acc[4][4];
#pragma unroll
  for (int i = 0; i < 4; ++i)
#pragma unroll
    for (int j = 0; j < 4; ++j) acc[i][j] = (f32x4){0.f, 0.f, 0.f, 0.f};
  const bf16* Abase = tb16 + ((size_t)(w * 64 + l16)) * 128 + quad * 8;
#pragma unroll
  for (int ks = 0; ks < 4; ++ks) {
    short8 af[4], bff[4];
#pragma unroll
    for (int mt = 0; mt < 4; ++mt)
      af[mt] = *(const short8*)(Abase + mt * 16 * 128 + ks * 32);
#pragma unroll
    for (int nt = 0; nt < 4; ++nt)
      bff[nt] = *(const short8*)(&BsT[nt * 16 + l16][ks * 32 + quad * 8]);
#pragma unroll
    for (int mt = 0; mt < 4; ++mt)
#pragma unroll
      for (int nt = 0; nt < 4; ++nt)
        acc[mt][nt] = mfma16(af[mt], bff[nt], acc[mt][nt]);
  }
#pragma unroll
  for (int nt = 0; nt < 4; ++nt) {
    int col = n0 + nt * 16 + l16;
    if (col >= TOTC) continue;
    float bias = b2[col];
#pragma unroll
    for (int mt = 0; mt < 4; ++mt) {
      int row0 = w * 64 + mt * 16 + quad * 4;
#pragma unroll
      for (int r = 0; r < 4; ++r)
        pchunk[(size_t)(row0 + r) * TOTC + col] = f2b(acc[mt][nt][r] + bias);
    }
  }
}

// ---------------- phase B: per-token MFMA mix ----------------
// h1 = gelu(S @ cm + m_beta); h2 = gelu(sm @ h1 + s_beta)
__global__ __launch_bounds__(256) void k_mix_mfma(const bf16* __restrict__ pchunk,
                                                  const bf16* __restrict__ S, int tok0,
                                                  const float* __restrict__ m_beta,
                                                  const float* __restrict__ s_beta,
                                                  bf16* __restrict__ h2) {
  int ltok = blockIdx.x, tok = tok0 + ltok;
  int t = threadIdx.x, lane = t & 63, w = t >> 6;
  int quad = lane >> 4, l16 = lane & 15;
  __shared__ bf16 Ss[48][264];    // A-layout S, rows 36..47 zero
  __shared__ bf16 cmT[256][40];   // [d][c-chunk(32)]
  __shared__ bf16 h1T[256][72];   // [d][p], p 48..63 zero
  __shared__ bf16 smS[48][72];    // [q][p], zero-padded
  const bf16* cm = pchunk + (size_t)ltok * TOTC;
  const bf16* sm = cm + CM_SZ;
  {
    const bf16* Sg = S + (size_t)tok * 9216;
    for (int idx = t * 8; idx < 9216; idx += 2048) {
      int p = idx >> 8, c = idx & 255;
      *(short8*)&Ss[p][c] = *(const short8*)(Sg + idx);
    }
    for (int idx = t; idx < 1584; idx += 256) ((unsigned*)&Ss[36][0])[idx] = 0;
    for (int idx = t; idx < 1728; idx += 256) ((unsigned*)&smS[0][0])[idx] = 0;
  }
  __syncthreads();
  for (int idx = t; idx < 1296; idx += 256) {
    int q = idx / 36, p = idx - q * 36;
    smS[q][p] = sm[idx];
  }
  f32x4 acc[3][4];
#pragma unroll
  for (int i = 0; i < 3; ++i)
#pragma unroll
    for (int j = 0; j < 4; ++j) acc[i][j] = (f32x4){0.f, 0.f, 0.f, 0.f};
  for (int kc = 0; kc < 256; kc += 32) {
    __syncthreads();
#pragma unroll
    for (int pass = 0; pass < 4; ++pass) {
      int ci = (t >> 5) + pass * 8;
      int d0 = (t & 31) * 8;
      short8 v = *(const short8*)(cm + (size_t)(kc + ci) * 256 + d0);
#pragma unroll
      for (int j = 0; j < 8; ++j) cmT[d0 + j][ci] = ((const bf16*)&v)[j];
    }
    __syncthreads();
    short8 bff[4];
#pragma unroll
    for (int nt = 0; nt < 4; ++nt)
      bff[nt] = *(const short8*)&cmT[w * 64 + nt * 16 + l16][quad * 8];
#pragma unroll
    for (int mt = 0; mt < 3; ++mt) {
      short8 a = *(const short8*)&Ss[mt * 16 + l16][kc + quad * 8];
#pragma unroll
      for (int nt = 0; nt < 4; ++nt)
        acc[mt][nt] = mfma16(a, bff[nt], acc[mt][nt]);
    }
  }
  // h1T[d][p] = gelu(acc + m_beta[d]); pad rows p>=36 hold gelu(m_beta) but sm=0 there
#pragma unroll
  for (int nt = 0; nt < 4; ++nt) {
    int d = w * 64 + nt * 16 + l16;
    float mb = m_beta[d];
#pragma unroll
    for (int mt = 0; mt < 3; ++mt) {
      int p0 = mt * 16 + quad * 4;
#pragma unroll
      for (int r = 0; r < 4; ++r)
        h1T[d][p0 + r] = f2b(gelu_f(acc[mt][nt][r] + mb));
    }
  }
  {
    int d = w * 64 + lane;
    *(uint4*)&h1T[d][48] = (uint4){0, 0, 0, 0};
    *(uint4*)&h1T[d][56] = (uint4){0, 0, 0, 0};
  }
  __syncthreads();
  f32x4 acc2[3][4];
#pragma unroll
  for (int i = 0; i < 3; ++i)
#pragma unroll
    for (int j = 0; j < 4; ++j) acc2[i][j] = (f32x4){0.f, 0.f, 0.f, 0.f};
#pragma unroll
  for (int ks = 0; ks < 2; ++ks) {
    short8 a2[3], b2v[4];
#pragma unroll
    for (int mt = 0; mt < 3; ++mt)
      a2[mt] = *(const short8*)&smS[mt * 16 + l16][ks * 32 + quad * 8];
#pragma unroll
    for (int nt = 0; nt < 4; ++nt)
      b2v[nt] = *(const short8*)&h1T[w * 64 + nt * 16 + l16][ks * 32 + quad * 8];
#pragma unroll
    for (int mt = 0; mt < 3; ++mt)
#pragma unroll
      for (int nt = 0; nt < 4; ++nt)
        acc2[mt][nt] = mfma16(a2[mt], b2v[nt], acc2[mt][nt]);
  }
  bf16* h2p = h2 + (size_t)tok * 9216;
#pragma unroll
  for (int mt = 0; mt < 3; ++mt) {
#pragma unroll
    for (int r = 0; r < 4; ++r) {
      int q = mt * 16 + quad * 4 + r;
      if (q >= 36) continue;
      float sb = s_beta[q];
#pragma unroll
      for (int nt = 0; nt < 4; ++nt) {
        int d = w * 64 + nt * 16 + l16;
        h2p[q * 256 + d] = f2b(gelu_f(acc2[mt][nt][r] + sb));
      }
    }
  }
}

// ---------------- MFMA tiled GEMM: A bf16 (MxK), B f32 (KxN) -> part f32 ----------------
__global__ __launch_bounds__(256) void k_gemm_mfma(const bf16* __restrict__ A,
                                                   const float* __restrict__ Bm,
                                                   float* __restrict__ part,
                                                   int M, int N, int K) {
  int nb = blockIdx.x, mb = blockIdx.y, ks = blockIdx.z;
  int kchunk = K / gridDim.z;
  int k0 = ks * kchunk;
  __shared__ bf16 As[64][72];
  __shared__ bf16 BsT[64][72];
  int t = threadIdx.x, lane = t & 63, w = t >> 6;
  int quad = lane >> 4, l16 = lane & 15;
  int wm = (w >> 1) * 32, wn = (w & 1) * 32;
  f32x4 acc[2][2];
#pragma unroll
  for (int i = 0; i < 2; ++i)
#pragma unroll
    for (int j = 0; j < 2; ++j) acc[i][j] = (f32x4){0.f, 0.f, 0.f, 0.f};
  for (int kt = 0; kt < kchunk; kt += 64) {
    __syncthreads();
    {
      int m = t >> 2, kk = (t & 3) * 16;
      const bf16* gp = A + (size_t)(mb * 64 + m) * K + k0 + kt + kk;
      *(short8*)&As[m][kk] = *(const short8*)gp;
      *(short8*)&As[m][kk + 8] = *(const short8*)(gp + 8);
    }
    {
      int kk = t >> 4, nl = (t & 15) * 4;
#pragma unroll
      for (int pass = 0; pass < 4; ++pass) {
        int k = kk + pass * 16;
        const float4 v = *(const float4*)(Bm + (size_t)(k0 + kt + k) * N + nb * 64 + nl);
        BsT[nl + 0][k] = f2b(v.x);
        BsT[nl + 1][k] = f2b(v.y);
        BsT[nl + 2][k] = f2b(v.z);
        BsT[nl + 3][k] = f2b(v.w);
      }
    }
    __syncthreads();
#pragma unroll
    for (int kss = 0; kss < 2; ++kss) {
      short8 af[2], bff[2];
#pragma unroll
      for (int mt = 0; mt < 2; ++mt)
        af[mt] = *(const short8*)&As[wm + mt * 16 + l16][kss * 32 + quad * 8];
#pragma unroll
      for (int nt = 0; nt < 2; ++nt)
        bff[nt] = *(const short8*)&BsT[wn + nt * 16 + l16][kss * 32 + quad * 8];
#pragma unroll
      for (int mt = 0; mt < 2; ++mt)
#pragma unroll
        for (int nt = 0; nt < 2; ++nt)
          acc[mt][nt] = mfma16(af[mt], bff[nt], acc[mt][nt]);
    }
  }
#pragma unroll
  for (int mt = 0; mt < 2; ++mt)
#pragma unroll
    for (int r = 0; r < 4; ++r) {
      int m = mb * 64 + wm + mt * 16 + quad * 4 + r;
#pragma unroll
      for (int nt = 0; nt < 2; ++nt) {
        int n = nb * 64 + wn + nt * 16 + l16;
        part[(size_t)ks * M * N + (size_t)m * N + n] = acc[mt][nt][r];
      }
    }
}

// ---------------- epilogue ----------------
__global__ __launch_bounds__(256) void k_epi(const float* __restrict__ part, int S_,
                                             int MN, int N, const float* __restrict__ bias,
                                             const float* __restrict__ resf, int do_gelu,
                                             float* __restrict__ outf, bf16* __restrict__ outh) {
  int idx = blockIdx.x * 256 + threadIdx.x;
  if (idx >= MN) return;
  int n = idx % N;
  float a = 0.f;
  for (int s = 0; s < S_; ++s) a += part[(size_t)s * MN + idx];
  a += bias[n];
  if (resf) a += resf[idx];
  if (do_gelu) a = gelu_f(a);
  if (outf) outf[idx] = a;
  if (outh) outh[idx] = f2b(a);
}

// ---------------- LayerNorm: f32 in -> bf16 out ----------------
__global__ __launch_bounds__(256) void k_ln(const float* __restrict__ x,
                                            const float* __restrict__ g,
                                            const float* __restrict__ b,
                                            bf16* __restrict__ out) {
  int tok = blockIdx.x, t = threadIdx.x, lane = t & 63, w = t >> 6;
  __shared__ float wsum[4];
  size_t base = (size_t)tok * 512;
  float a0 = x[base + t], a1 = x[base + t + 256];
  float s = a0 + a1;
#pragma unroll
  for (int o = 32; o; o >>= 1) s += __shfl_xor(s, o);
  if (lane == 0) wsum[w] = s;
  __syncthreads();
  float mean = (wsum[0] + wsum[1] + wsum[2] + wsum[3]) * (1.0f / 512.0f);
  float d0 = a0 - mean, d1 = a1 - mean;
  float ss = d0 * d0 + d1 * d1;
#pragma unroll
  for (int o = 32; o; o >>= 1) ss += __shfl_xor(ss, o);
  __syncthreads();
  if (lane == 0) wsum[w] = ss;
  __syncthreads();
  float var = (wsum[0] + wsum[1] + wsum[2] + wsum[3]) * (1.0f / 512.0f);
  float rstd = rsqrtf(var + 1e-5f);
  out[base + t] = f2b(d0 * rstd * g[t] + b[t]);
  out[base + t + 256] = f2b(d1 * rstd * g[t + 256] + b[t + 256]);
}

// ---------------- attention ----------------
__global__ __launch_bounds__(256) void k_attn(const float* __restrict__ qkvf,
                                              bf16* __restrict__ obuf) {
  int b = blockIdx.x >> 3, h = blockIdx.x & 7;
  __shared__ float kT[64][65];
  __shared__ float vT[64][65];
  __shared__ float att[64][65];
  int t = threadIdx.x, lane = t & 63, w = t >> 6;
#pragma unroll
  for (int i = 0; i < 16; ++i) {
    int idx = t + i * 256;
    int j = idx >> 6, d = idx & 63;
    size_t tb = (size_t)(b * 64 + j) * 1536 + h * 64 + d;
    kT[j][d] = qkvf[tb + 512];
    vT[j][d] = qkvf[tb + 1024];
  }
  __syncthreads();
#pragma unroll 4
  for (int m = 0; m < 16; ++m) {
    int i = w * 16 + m;
    const float* qrow = &qkvf[(size_t)(b * 64 + i) * 1536 + h * 64];
    float s = 0.f;
    for (int d = 0; d < 64; ++d) s = fmaf(qrow[d], kT[lane][d], s);
    s *= 0.125f;
    float mx = s;
#pragma unroll
    for (int o = 32; o; o >>= 1) mx = fmaxf(mx, __shfl_xor(mx, o));
    float e = expf(s - mx);
    float sum = e;
#pragma unroll
    for (int o = 32; o; o >>= 1) sum += __shfl_xor(sum, o);
    att[i][lane] = e / sum;
  }
  __syncthreads();
#pragma unroll 4
  for (int m = 0; m < 16; ++m) {
    int i = w * 16 + m;
    float o = 0.f;
    for (int j = 0; j < 64; ++j) o = fmaf(att[i][j], vT[j][lane], o);
    obuf[(size_t)(b * 64 + i) * 512 + h * 64 + lane] = f2b(o);
  }
}

extern "C" void kernel_launch(void* const* d_in, const int* in_sizes, int n_in,
                              void* d_out, int out_size, void* d_ws, size_t ws_size,
                              hipStream_t stream) {
  const float* te = (const float*)d_in[0];
  const float* roi = (const float*)d_in[1];
  const float* img = (const float*)d_in[2];
  const float* ln_off_g = (const float*)d_in[3];
  const float* ln_off_b = (const float*)d_in[4];
  const float* w_off = (const float*)d_in[5];
  const float* off_bias = (const float*)d_in[6];
  const float* ln_pg_g = (const float*)d_in[7];
  const float* ln_pg_b = (const float*)d_in[8];
  const float* w_pg1 = (const float*)d_in[9];
  const float* b_pg1 = (const float*)d_in[10];
  const float* w_pg2 = (const float*)d_in[11];
  const float* b_pg2 = (const float*)d_in[12];
  const float* m_beta = (const float*)d_in[13];
  const float* s_beta = (const float*)d_in[14];
  const float* w_out = (const float*)d_in[15];
  const float* b_out = (const float*)d_in[16];
  const float* ln1_g = (const float*)d_in[17];
  const float* ln1_b = (const float*)d_in[18];
  const float* w_qkv = (const float*)d_in[19];
  const float* b_qkv = (const float*)d_in[20];
  const float* w_proj = (const float*)d_in[21];
  const float* b_proj = (const float*)d_in[22];
  const float* ln2_g = (const float*)d_in[23];
  const float* ln2_b = (const float*)d_in[24];
  const float* w_fc1 = (const float*)d_in[25];
  const float* b_fc1 = (const float*)d_in[26];
  const float* w_fc2 = (const float*)d_in[27];
  const float* b_fc2 = (const float*)d_in[28];

  char* ws = (char*)d_ws;
  // Region A: imgT [0, 64M), dead after k_sample; overlaid by post-sample buffers
  bf16* imgT = (bf16*)ws;
  char* ov = ws;
  bf16* h2 = (bf16*)ov; ov += 9437184;
  float* part = (float*)ov; ov += 8388608;
  float* x1 = (float*)ov; ov += 1048576;
  float* xa = (float*)ov; ov += 1048576;
  float* qkvf = (float*)ov; ov += 3145728;
  bf16* ln1buf = (bf16*)ov; ov += 524288;
  bf16* ln2buf = (bf16*)ov; ov += 524288;
  bf16* obuf = (bf16*)ov; ov += 524288;
  bf16* hfc = (bf16*)ov; ov += 2097152;
  // Region B: persistent tail
  char* tail = ws + 67108864;
  bf16* Sbuf = (bf16*)tail; tail += 9437184;       // 512*36*256 bf16
  bf16* tb16 = (bf16*)tail; tail += 131072;        // 512*128 bf16
  int* meta_i = (int*)tail; tail += 294912;
  float* meta_w = (float*)tail; tail += 294912;
  bf16* pchunk = (bf16*)tail; tail += (size_t)TCHUNK * TOTC * 2;  // 34.2 MB
  (void)ws_size;

  k_transpose<<<dim3(512, 8), 256, 0, stream>>>(img, imgT);
  k_prep<<<512, 256, 0, stream>>>(te, roi, ln_off_g, ln_off_b, w_off, off_bias,
                                  ln_pg_g, ln_pg_b, w_pg1, b_pg1, tb16, meta_i, meta_w);
  k_sample<<<512, 256, 0, stream>>>(imgT, meta_i, meta_w, Sbuf);
  for (int c = 0; c < NTOK / TCHUNK; ++c) {
    int t0 = c * TCHUNK;
    k_pg2_mfma<<<1045, 256, 0, stream>>>(tb16 + (size_t)t0 * 128, w_pg2, b_pg2, pchunk);
    k_mix_mfma<<<TCHUNK, 256, 0, stream>>>(pchunk, Sbuf, t0, m_beta, s_beta, h2);
  }

  k_gemm_mfma<<<dim3(8, 8, 8), 256, 0, stream>>>(h2, w_out, part, 512, 512, 9216);
  k_epi<<<1024, 256, 0, stream>>>(part, 8, 512 * 512, 512, b_out, te, 0, x1, nullptr);

  k_ln<<<512, 256, 0, stream>>>(x1, ln1_g, ln1_b, ln1buf);
  k_gemm_mfma<<<dim3(24, 8, 2), 256, 0, stream>>>(ln1buf, w_qkv, part, 512, 1536, 512);
  k_epi<<<3072, 256, 0, stream>>>(part, 2, 512 * 1536, 1536, b_qkv, nullptr, 0, qkvf, nullptr);
  k_attn<<<64, 256, 0, stream>>>(qkvf, obuf);
  k_gemm_mfma<<<dim3(8, 8, 4), 256, 0, stream>>>(obuf, w_proj, part, 512, 512, 512);
  k_epi<<<1024, 256, 0, stream>>>(part, 4, 512 * 512, 512, b_proj, x1, 0, xa, nullptr);

  k_ln<<<512, 256, 0, stream>>>(xa, ln2_g, ln2_b, ln2buf);
  k_gemm_mfma<<<dim3(32, 8, 2), 256, 0, stream>>>(ln2buf, w_fc1, part, 512, 2048, 512);
  k_epi<<<4096, 256, 0, stream>>>(part, 2, 512 * 2048, 2048, b_fc1, nullptr, 1, nullptr, hfc);
  k_gemm_mfma<<<dim3(8, 8, 4), 256, 0, stream>>>(hfc, w_fc2, part, 512, 512, 2048);
  k_epi<<<1024, 256, 0, stream>>>(part, 4, 512 * 512, 512, b_fc2, xa, 0, (float*)d_out, nullptr);
}

// Round 4
// 568.721 us; speedup vs baseline: 1.9971x; 1.1599x over previous
//
#include <hip/hip_runtime.h>
#include <hip/hip_bf16.h>

typedef __hip_bfloat16 bf16;
typedef __attribute__((ext_vector_type(8))) short short8;
typedef __attribute__((ext_vector_type(4))) float f32x4;

#define NTOK 512
#define TOTC 66832
#define CM_SZ 65536

__device__ __forceinline__ float b2f(bf16 x) { return __bfloat162float(x); }
__device__ __forceinline__ bf16 f2b(float x) { return __float2bfloat16(x); }
__device__ __forceinline__ float gelu_f(float x) {
  return 0.5f * x * (1.0f + erff(x * 0.7071067811865476f));
}
__device__ __forceinline__ f32x4 mfma16(short8 a, short8 b, f32x4 c) {
  return __builtin_amdgcn_mfma_f32_16x16x32_bf16(a, b, c, 0, 0, 0);
}

// ---------------- img_feat (B,C,H,W) f32 -> (B,H,W,C) bf16 ----------------
__global__ __launch_bounds__(256) void k_transpose(const float* __restrict__ img,
                                                   bf16* __restrict__ imgT) {
  int b = blockIdx.y;
  int hw0 = blockIdx.x * 32;
  __shared__ float tile[256][33];
  int t = threadIdx.x;
  int hw = t & 31, c0 = t >> 5;
#pragma unroll 8
  for (int i = 0; i < 32; ++i) {
    int c = c0 + 8 * i;
    tile[c][hw] = img[((size_t)(b * 256 + c) << 14) + hw0 + hw];
  }
  __syncthreads();
#pragma unroll 8
  for (int i = 0; i < 32; ++i) {
    imgT[(((size_t)b << 14) + hw0 + i) * 256 + t] = f2b(tile[t][i]);
  }
}

// ---------------- per-token prep ----------------
__global__ __launch_bounds__(256) void k_prep(
    const float* __restrict__ te, const float* __restrict__ roi,
    const float* __restrict__ g_off, const float* __restrict__ b_off,
    const float* __restrict__ w_off, const float* __restrict__ off_bias,
    const float* __restrict__ g_pg, const float* __restrict__ b_pg,
    const float* __restrict__ w_pg1, const float* __restrict__ b_pg1,
    bf16* __restrict__ t_out, int* __restrict__ meta_i, float* __restrict__ meta_w) {
  int tok = blockIdx.x;
  int t = threadIdx.x, lane = t & 63, w = t >> 6;
  __shared__ float xo[512], xq[512], offb[72], red[4], wsum[4];
  size_t base = (size_t)tok * 512;
  float a0 = te[base + t];
  float a1 = te[base + t + 256];
  float s = a0 + a1;
#pragma unroll
  for (int o = 32; o; o >>= 1) s += __shfl_xor(s, o);
  if (lane == 0) wsum[w] = s;
  __syncthreads();
  float mean = (wsum[0] + wsum[1] + wsum[2] + wsum[3]) * (1.0f / 512.0f);
  float d0 = a0 - mean, d1 = a1 - mean;
  float ss = d0 * d0 + d1 * d1;
#pragma unroll
  for (int o = 32; o; o >>= 1) ss += __shfl_xor(ss, o);
  __syncthreads();
  if (lane == 0) wsum[w] = ss;
  __syncthreads();
  float var = (wsum[0] + wsum[1] + wsum[2] + wsum[3]) * (1.0f / 512.0f);
  float rstd = rsqrtf(var + 1e-5f);
  xo[t] = d0 * rstd * g_off[t] + b_off[t];
  xo[t + 256] = d1 * rstd * g_off[t + 256] + b_off[t + 256];
  xq[t] = d0 * rstd * g_pg[t] + b_pg[t];
  xq[t + 256] = d1 * rstd * g_pg[t + 256] + b_pg[t + 256];
  __syncthreads();
  if (t < 128) {
    float acc = b_pg1[t];
    for (int d = 0; d < 512; ++d) acc = fmaf(xq[d], w_pg1[d * 128 + t], acc);
    t_out[(size_t)tok * 128 + t] = f2b(acc);
  } else if (t < 200) {
    int j = t - 128;
    float acc = off_bias[j];
    for (int d = 0; d < 512; ++d) acc = fmaf(xo[d], w_off[d * 72 + j], acc);
    offb[j] = acc;
  }
  __syncthreads();
  if (t < 2) {
    float mu = 0.f;
    for (int p = 0; p < 36; ++p) mu += offb[p * 2 + t];
    mu *= (1.0f / 36.0f);
    float s2 = 0.f;
    for (int p = 0; p < 36; ++p) { float dd = offb[p * 2 + t] - mu; s2 += dd * dd; }
    float sd = sqrtf(s2 * (1.0f / 35.0f)) + 1e-5f;  // ddof=1, then +1e-5
    red[t] = mu;
    red[2 + t] = 1.0f / (3.0f * sd);
  }
  __syncthreads();
  if (t < 36) {
    int p = t;
    float r0 = roi[tok * 4 + 0], r1 = roi[tok * 4 + 1];
    float r2 = roi[tok * 4 + 2], r3 = roi[tok * 4 + 3];
    float cx = (r0 + r2) * 0.5f, cy = (r1 + r3) * 0.5f;
    float bw = r2 - r0, bh = r3 - r1;
    float ox = (offb[p * 2 + 0] - red[0]) * red[2];
    float oy = (offb[p * 2 + 1] - red[1]) * red[3];
    float fx = (cx + ox * bw) * 128.0f - 0.5f;
    float fy = (cy + oy * bh) * 128.0f - 0.5f;
    float x0f = floorf(fx), y0f = floorf(fy);
    float wx = fx - x0f, wy = fy - y0f;
    int x0 = min(max((int)x0f, 0), 127);
    int x1 = min(max((int)x0f + 1, 0), 127);
    int y0 = min(max((int)y0f, 0), 127);
    int y1 = min(max((int)y0f + 1, 0), 127);
    int ibase = (tok >> 6) * 16384;
    int mi = (tok * 36 + p) * 4;
    meta_i[mi + 0] = (ibase + y0 * 128 + x0) * 256;
    meta_i[mi + 1] = (ibase + y0 * 128 + x1) * 256;
    meta_i[mi + 2] = (ibase + y1 * 128 + x0) * 256;
    meta_i[mi + 3] = (ibase + y1 * 128 + x1) * 256;
    meta_w[mi + 0] = (1.f - wx) * (1.f - wy);
    meta_w[mi + 1] = wx * (1.f - wy);
    meta_w[mi + 2] = (1.f - wx) * wy;
    meta_w[mi + 3] = wx * wy;
  }
}

// ---------------- bilinear gather -> S bf16 ----------------
__global__ __launch_bounds__(256) void k_sample(const bf16* __restrict__ imgT,
                                                const int* __restrict__ meta_i,
                                                const float* __restrict__ meta_w,
                                                bf16* __restrict__ S) {
  int tok = blockIdx.x, t = threadIdx.x;
  for (int p = 0; p < 36; ++p) {
    int mi = (tok * 36 + p) * 4;
    int o00 = meta_i[mi + 0], o01 = meta_i[mi + 1], o10 = meta_i[mi + 2], o11 = meta_i[mi + 3];
    float w00 = meta_w[mi + 0], w01 = meta_w[mi + 1], w10 = meta_w[mi + 2], w11 = meta_w[mi + 3];
    float v = w00 * b2f(imgT[o00 + t]) + w01 * b2f(imgT[o01 + t]) +
              w10 * b2f(imgT[o10 + t]) + w11 * b2f(imgT[o11 + t]);
    S[((size_t)tok * 36 + p) * 256 + t] = f2b(v);
  }
}

// ---------------- convert+transpose all transformer weights f32 KxN -> bf16 NxK ----------------
__global__ __launch_bounds__(256) void k_wt(const float* __restrict__ w0, bf16* __restrict__ o0,
                                            const float* __restrict__ w1, bf16* __restrict__ o1,
                                            const float* __restrict__ w2, bf16* __restrict__ o2,
                                            const float* __restrict__ w3, bf16* __restrict__ o3,
                                            const float* __restrict__ w4, bf16* __restrict__ o4) {
  int b = blockIdx.x;
  const float* W;
  bf16* O;
  int K, N, loc;
  if (b < 4608) { W = w0; O = o0; K = 9216; N = 512; loc = b; }
  else if (b < 5376) { W = w1; O = o1; K = 512; N = 1536; loc = b - 4608; }
  else if (b < 5632) { W = w2; O = o2; K = 512; N = 512; loc = b - 5376; }
  else if (b < 6656) { W = w3; O = o3; K = 512; N = 2048; loc = b - 5632; }
  else { W = w4; O = o4; K = 2048; N = 512; loc = b - 6656; }
  int ntn = N >> 5;
  int nb = loc % ntn, kb = loc / ntn;
  int n0 = nb * 32, k0 = kb * 32;
  __shared__ float tl[32][33];
  int t = threadIdx.x, r = t >> 5, c = t & 31;
#pragma unroll
  for (int i = 0; i < 4; ++i)
    tl[r + 8 * i][c] = W[(size_t)(k0 + r + 8 * i) * N + n0 + c];
  __syncthreads();
#pragma unroll
  for (int i = 0; i < 4; ++i)
    O[(size_t)(n0 + r + 8 * i) * K + k0 + c] = f2b(tl[c][r + 8 * i]);
}

// ---------------- params = tb16(512x128) @ w_pg2(128xTOTC) + b_pg2, bf16 ----------------
__global__ __launch_bounds__(256) void k_pg2_mfma(const bf16* __restrict__ tb16,
                                                  const float* __restrict__ w2,
                                                  const float* __restrict__ b2,
                                                  bf16* __restrict__ pchunk) {
  int n0 = blockIdx.x * 64;
  int row0 = blockIdx.y * 256;
  int t = threadIdx.x, lane = t & 63, w = t >> 6;
  int quad = lane >> 4, l16 = lane & 15;
  __shared__ bf16 BsT[64][136];
  {
    int nl = (t & 15) * 4, kk = t >> 4;
#pragma unroll
    for (int pass = 0; pass < 8; ++pass) {
      int k = kk + pass * 16;
      int n = n0 + nl;
      int nc = (n + 3 < TOTC) ? n : (TOTC - 4);
      const float4 v = *(const float4*)(w2 + (size_t)k * TOTC + nc);
      BsT[nl + 0][k] = f2b(v.x);
      BsT[nl + 1][k] = f2b(v.y);
      BsT[nl + 2][k] = f2b(v.z);
      BsT[nl + 3][k] = f2b(v.w);
    }
  }
  __syncthreads();
  f32x4 acc[4][4];
#pragma unroll
  for (int i = 0; i < 4; ++i)
#pragma unroll
    for (int j = 0; j < 4; ++j) acc[i][j] = (f32x4){0.f, 0.f, 0.f, 0.f};
  const bf16* Abase = tb16 + ((size_t)(row0 + w * 64 + l16)) * 128 + quad * 8;
#pragma unroll
  for (int ks = 0; ks < 4; ++ks) {
    short8 af[4], bff[4];
#pragma unroll
    for (int mt = 0; mt < 4; ++mt)
      af[mt] = *(const short8*)(Abase + mt * 16 * 128 + ks * 32);
#pragma unroll
    for (int nt = 0; nt < 4; ++nt)
      bff[nt] = *(const short8*)(&BsT[nt * 16 + l16][ks * 32 + quad * 8]);
#pragma unroll
    for (int mt = 0; mt < 4; ++mt)
#pragma unroll
      for (int nt = 0; nt < 4; ++nt)
        acc[mt][nt] = mfma16(af[mt], bff[nt], acc[mt][nt]);
  }
#pragma unroll
  for (int nt = 0; nt < 4; ++nt) {
    int col = n0 + nt * 16 + l16;
    if (col >= TOTC) continue;
    float bias = b2[col];
#pragma unroll
    for (int mt = 0; mt < 4; ++mt) {
      int r0 = row0 + w * 64 + mt * 16 + quad * 4;
#pragma unroll
      for (int r = 0; r < 4; ++r)
        pchunk[(size_t)(r0 + r) * TOTC + col] = f2b(acc[mt][nt][r] + bias);
    }
  }
}

// ---------------- per-token cm (256x256) transpose -> pcmT[tok][d][c] ----------------
__global__ __launch_bounds__(256) void k_cmT(const bf16* __restrict__ pchunk,
                                             bf16* __restrict__ pcmT) {
  int tok = blockIdx.y;
  int c0 = (blockIdx.x & 3) * 64, d0 = (blockIdx.x >> 2) * 64;
  __shared__ bf16 tl[64][72];
  int t = threadIdx.x;
  {
    int c = t >> 2, dl = (t & 3) * 16;
    const bf16* src = pchunk + (size_t)tok * TOTC + (size_t)(c0 + c) * 256 + d0 + dl;
    *(short8*)&tl[c][dl] = *(const short8*)src;
    *(short8*)&tl[c][dl + 8] = *(const short8*)(src + 8);
  }
  __syncthreads();
  {
    int dr = t & 63, cc = (t >> 6) * 16;
    bf16 tmp[16];
#pragma unroll
    for (int i = 0; i < 16; ++i) tmp[i] = tl[cc + i][dr];
    bf16* dst = pcmT + (size_t)tok * 65536 + (size_t)(d0 + dr) * 256 + c0 + cc;
    *(short8*)dst = *(const short8*)tmp;
    *(short8*)(dst + 8) = *(const short8*)(tmp + 8);
  }
}

// ---------------- mix: h1 = gelu(S@cm + m_beta); h2 = gelu(sm@h1 + s_beta) ----------------
// block = (token, d-half of 128). No LDS in K-loop; A/B fragments direct from global.
__global__ __launch_bounds__(256) void k_mix3(const bf16* __restrict__ pchunk,
                                              const bf16* __restrict__ pcmT,
                                              const bf16* __restrict__ S,
                                              const float* __restrict__ m_beta,
                                              const float* __restrict__ s_beta,
                                              bf16* __restrict__ h2) {
  int tok = blockIdx.x, dh = blockIdx.y * 128;
  int t = threadIdx.x, lane = t & 63, w = t >> 6;
  int quad = lane >> 4, l16 = lane & 15;
  __shared__ bf16 h1T[128][72];  // [d_local][p], p 36..63 zeroed
  __shared__ bf16 smS[48][72];   // [q][p] zero-padded
  for (int i = t; i < 1728; i += 256) ((unsigned*)smS)[i] = 0u;
  __syncthreads();
  const bf16* sm = pchunk + (size_t)tok * TOTC + CM_SZ;
  for (int i = t; i < 1296; i += 256) {
    int q = i / 36, p = i - q * 36;
    smS[q][p] = sm[i];
  }
  f32x4 acc[3][2];
#pragma unroll
  for (int i = 0; i < 3; ++i)
#pragma unroll
    for (int j = 0; j < 2; ++j) acc[i][j] = (f32x4){0.f, 0.f, 0.f, 0.f};
  const bf16* Sg = S + (size_t)tok * 9216;
  const bf16* Cg = pcmT + (size_t)tok * 65536;
  int dw = w * 32;
#pragma unroll
  for (int kc = 0; kc < 256; kc += 32) {
    short8 a[3], b[2];
#pragma unroll
    for (int mt = 0; mt < 3; ++mt)
      a[mt] = *(const short8*)(Sg + (size_t)(mt * 16 + l16) * 256 + kc + quad * 8);
#pragma unroll
    for (int nt = 0; nt < 2; ++nt)
      b[nt] = *(const short8*)(Cg + (size_t)(dh + dw + nt * 16 + l16) * 256 + kc + quad * 8);
#pragma unroll
    for (int mt = 0; mt < 3; ++mt)
#pragma unroll
      for (int nt = 0; nt < 2; ++nt)
        acc[mt][nt] = mfma16(a[mt], b[nt], acc[mt][nt]);
  }
#pragma unroll
  for (int nt = 0; nt < 2; ++nt) {
    int dl = dw + nt * 16 + l16;
    float mb = m_beta[dh + dl];
#pragma unroll
    for (int mt = 0; mt < 3; ++mt)
#pragma unroll
      for (int r = 0; r < 4; ++r) {
        int p = mt * 16 + quad * 4 + r;
        if (p < 36) h1T[dl][p] = f2b(gelu_f(acc[mt][nt][r] + mb));
      }
  }
  for (int i = t; i < 128 * 28; i += 256) {
    int d = i / 28, p = 36 + i % 28;
    h1T[d][p] = (bf16)0.f;
  }
  __syncthreads();
  f32x4 acc2[3][2];
#pragma unroll
  for (int i = 0; i < 3; ++i)
#pragma unroll
    for (int j = 0; j < 2; ++j) acc2[i][j] = (f32x4){0.f, 0.f, 0.f, 0.f};
#pragma unroll
  for (int ks = 0; ks < 2; ++ks) {
    short8 a2[3], b2v[2];
#pragma unroll
    for (int mt = 0; mt < 3; ++mt)
      a2[mt] = *(const short8*)&smS[mt * 16 + l16][ks * 32 + quad * 8];
#pragma unroll
    for (int nt = 0; nt < 2; ++nt)
      b2v[nt] = *(const short8*)&h1T[dw + nt * 16 + l16][ks * 32 + quad * 8];
#pragma unroll
    for (int mt = 0; mt < 3; ++mt)
#pragma unroll
      for (int nt = 0; nt < 2; ++nt)
        acc2[mt][nt] = mfma16(a2[mt], b2v[nt], acc2[mt][nt]);
  }
  bf16* h2p = h2 + (size_t)tok * 9216 + dh;
#pragma unroll
  for (int mt = 0; mt < 3; ++mt)
#pragma unroll
    for (int r = 0; r < 4; ++r) {
      int q = mt * 16 + quad * 4 + r;
      if (q >= 36) continue;
      float sb = s_beta[q];
#pragma unroll
      for (int nt = 0; nt < 2; ++nt)
        h2p[q * 256 + dw + nt * 16 + l16] = f2b(gelu_f(acc2[mt][nt][r] + sb));
    }
}

// ---------------- MFMA tiled GEMM: A bf16 MxK, BT bf16 NxK -> part f32 ----------------
__global__ __launch_bounds__(256) void k_gemm_bt(const bf16* __restrict__ A,
                                                 const bf16* __restrict__ BT,
                                                 float* __restrict__ part,
                                                 int M, int N, int K) {
  int nb = blockIdx.x, mb = blockIdx.y, ks = blockIdx.z;
  int kchunk = K / gridDim.z;
  int k0 = ks * kchunk;
  __shared__ bf16 As[64][72], Bs[64][72];
  int t = threadIdx.x, lane = t & 63, w = t >> 6;
  int quad = lane >> 4, l16 = lane & 15;
  int wm = (w >> 1) * 32, wn = (w & 1) * 32;
  int r = t >> 2, kk = (t & 3) * 16;
  f32x4 acc[2][2];
#pragma unroll
  for (int i = 0; i < 2; ++i)
#pragma unroll
    for (int j = 0; j < 2; ++j) acc[i][j] = (f32x4){0.f, 0.f, 0.f, 0.f};
  for (int kt = 0; kt < kchunk; kt += 64) {
    __syncthreads();
    const bf16* ga = A + (size_t)(mb * 64 + r) * K + k0 + kt + kk;
    *(short8*)&As[r][kk] = *(const short8*)ga;
    *(short8*)&As[r][kk + 8] = *(const short8*)(ga + 8);
    const bf16* gb = BT + (size_t)(nb * 64 + r) * K + k0 + kt + kk;
    *(short8*)&Bs[r][kk] = *(const short8*)gb;
    *(short8*)&Bs[r][kk + 8] = *(const short8*)(gb + 8);
    __syncthreads();
#pragma unroll
    for (int kss = 0; kss < 2; ++kss) {
      short8 af[2], bff[2];
#pragma unroll
      for (int mt = 0; mt < 2; ++mt)
        af[mt] = *(const short8*)&As[wm + mt * 16 + l16][kss * 32 + quad * 8];
#pragma unroll
      for (int nt = 0; nt < 2; ++nt)
        bff[nt] = *(const short8*)&Bs[wn + nt * 16 + l16][kss * 32 + quad * 8];
#pragma unroll
      for (int mt = 0; mt < 2; ++mt)
#pragma unroll
        for (int nt = 0; nt < 2; ++nt)
          acc[mt][nt] = mfma16(af[mt], bff[nt], acc[mt][nt]);
    }
  }
#pragma unroll
  for (int mt = 0; mt < 2; ++mt)
#pragma unroll
    for (int rr = 0; rr < 4; ++rr) {
      int m = mb * 64 + wm + mt * 16 + quad * 4 + rr;
#pragma unroll
      for (int nt = 0; nt < 2; ++nt) {
        int n = nb * 64 + wn + nt * 16 + l16;
        part[(size_t)ks * M * N + (size_t)m * N + n] = acc[mt][nt][rr];
      }
    }
}

// ---------------- epilogue ----------------
__global__ __launch_bounds__(256) void k_epi(const float* __restrict__ part, int S_,
                                             int MN, int N, const float* __restrict__ bias,
                                             const float* __restrict__ resf, int do_gelu,
                                             float* __restrict__ outf, bf16* __restrict__ outh) {
  int idx = blockIdx.x * 256 + threadIdx.x;
  if (idx >= MN) return;
  int n = idx % N;
  float a = 0.f;
  for (int s = 0; s < S_; ++s) a += part[(size_t)s * MN + idx];
  a += bias[n];
  if (resf) a += resf[idx];
  if (do_gelu) a = gelu_f(a);
  if (outf) outf[idx] = a;
  if (outh) outh[idx] = f2b(a);
}

// ---------------- LayerNorm: f32 in -> bf16 out ----------------
__global__ __launch_bounds__(256) void k_ln(const float* __restrict__ x,
                                            const float* __restrict__ g,
                                            const float* __restrict__ b,
                                            bf16* __restrict__ out) {
  int tok = blockIdx.x, t = threadIdx.x, lane = t & 63, w = t >> 6;
  __shared__ float wsum[4];
  size_t base = (size_t)tok * 512;
  float a0 = x[base + t], a1 = x[base + t + 256];
  float s = a0 + a1;
#pragma unroll
  for (int o = 32; o; o >>= 1) s += __shfl_xor(s, o);
  if (lane == 0) wsum[w] = s;
  __syncthreads();
  float mean = (wsum[0] + wsum[1] + wsum[2] + wsum[3]) * (1.0f / 512.0f);
  float d0 = a0 - mean, d1 = a1 - mean;
  float ss = d0 * d0 + d1 * d1;
#pragma unroll
  for (int o = 32; o; o >>= 1) ss += __shfl_xor(ss, o);
  __syncthreads();
  if (lane == 0) wsum[w] = ss;
  __syncthreads();
  float var = (wsum[0] + wsum[1] + wsum[2] + wsum[3]) * (1.0f / 512.0f);
  float rstd = rsqrtf(var + 1e-5f);
  out[base + t] = f2b(d0 * rstd * g[t] + b[t]);
  out[base + t + 256] = f2b(d1 * rstd * g[t + 256] + b[t + 256]);
}

// ---------------- attention ----------------
__global__ __launch_bounds__(256) void k_attn(const float* __restrict__ qkvf,
                                              bf16* __restrict__ obuf) {
  int b = blockIdx.x >> 3, h = blockIdx.x & 7;
  __shared__ float kT[64][65];
  __shared__ float vT[64][65];
  __shared__ float att[64][65];
  int t = threadIdx.x, lane = t & 63, w = t >> 6;
#pragma unroll
  for (int i = 0; i < 16; ++i) {
    int idx = t + i * 256;
    int j = idx >> 6, d = idx & 63;
    size_t tb = (size_t)(b * 64 + j) * 1536 + h * 64 + d;
    kT[j][d] = qkvf[tb + 512];
    vT[j][d] = qkvf[tb + 1024];
  }
  __syncthreads();
#pragma unroll 4
  for (int m = 0; m < 16; ++m) {
    int i = w * 16 + m;
    const float* qrow = &qkvf[(size_t)(b * 64 + i) * 1536 + h * 64];
    float s = 0.f;
    for (int d = 0; d < 64; ++d) s = fmaf(qrow[d], kT[lane][d], s);
    s *= 0.125f;
    float mx = s;
#pragma unroll
    for (int o = 32; o; o >>= 1) mx = fmaxf(mx, __shfl_xor(mx, o));
    float e = expf(s - mx);
    float sum = e;
#pragma unroll
    for (int o = 32; o; o >>= 1) sum += __shfl_xor(sum, o);
    att[i][lane] = e / sum;
  }
  __syncthreads();
#pragma unroll 4
  for (int m = 0; m < 16; ++m) {
    int i = w * 16 + m;
    float o = 0.f;
    for (int j = 0; j < 64; ++j) o = fmaf(att[i][j], vT[j][lane], o);
    obuf[(size_t)(b * 64 + i) * 512 + h * 64 + lane] = f2b(o);
  }
}

extern "C" void kernel_launch(void* const* d_in, const int* in_sizes, int n_in,
                              void* d_out, int out_size, void* d_ws, size_t ws_size,
                              hipStream_t stream) {
  const float* te = (const float*)d_in[0];
  const float* roi = (const float*)d_in[1];
  const float* img = (const float*)d_in[2];
  const float* ln_off_g = (const float*)d_in[3];
  const float* ln_off_b = (const float*)d_in[4];
  const float* w_off = (const float*)d_in[5];
  const float* off_bias = (const float*)d_in[6];
  const float* ln_pg_g = (const float*)d_in[7];
  const float* ln_pg_b = (const float*)d_in[8];
  const float* w_pg1 = (const float*)d_in[9];
  const float* b_pg1 = (const float*)d_in[10];
  const float* w_pg2 = (const float*)d_in[11];
  const float* b_pg2 = (const float*)d_in[12];
  const float* m_beta = (const float*)d_in[13];
  const float* s_beta = (const float*)d_in[14];
  const float* w_out = (const float*)d_in[15];
  const float* b_out = (const float*)d_in[16];
  const float* ln1_g = (const float*)d_in[17];
  const float* ln1_b = (const float*)d_in[18];
  const float* w_qkv = (const float*)d_in[19];
  const float* b_qkv = (const float*)d_in[20];
  const float* w_proj = (const float*)d_in[21];
  const float* b_proj = (const float*)d_in[22];
  const float* ln2_g = (const float*)d_in[23];
  const float* ln2_b = (const float*)d_in[24];
  const float* w_fc1 = (const float*)d_in[25];
  const float* b_fc1 = (const float*)d_in[26];
  const float* w_fc2 = (const float*)d_in[27];
  const float* b_fc2 = (const float*)d_in[28];

  char* ws = (char*)d_ws;
  // Region A: imgT [0, 64M); dead after k_sample; overlaid by transformer buffers
  bf16* imgT = (bf16*)ws;
  char* ov = ws;
  bf16* h2 = (bf16*)ov; ov += 9437184;
  float* part = (float*)ov; ov += 8388608;
  float* x1 = (float*)ov; ov += 1048576;
  float* xa = (float*)ov; ov += 1048576;
  float* qkvf = (float*)ov; ov += 3145728;
  bf16* ln1buf = (bf16*)ov; ov += 524288;
  bf16* ln2buf = (bf16*)ov; ov += 524288;
  bf16* obuf = (bf16*)ov; ov += 524288;
  bf16* hfc = (bf16*)ov; ov += 2097152;
  // Region B: persistent tail
  char* tail = ws + 67108864;
  bf16* Sbuf = (bf16*)tail; tail += 9437184;        // 512*36*256 bf16
  bf16* tb16 = (bf16*)tail; tail += 131072;         // 512*128 bf16 (also OOB-read pad for Sbuf)
  int* meta_i = (int*)tail; tail += 294912;
  float* meta_w = (float*)tail; tail += 294912;
  bf16* pchunk = (bf16*)tail; tail += (size_t)NTOK * TOTC * 2;   // 68.4 MB
  bf16* pcmT = (bf16*)tail; tail += (size_t)NTOK * 65536 * 2;    // 67.1 MB
  bf16* w_outT = (bf16*)tail; tail += 9437184;
  bf16* w_qkvT = (bf16*)tail; tail += 1572864;
  bf16* w_projT = (bf16*)tail; tail += 524288;
  bf16* w_fc1T = (bf16*)tail; tail += 2097152;
  bf16* w_fc2T = (bf16*)tail; tail += 2097152;
  (void)ws_size;

  k_transpose<<<dim3(512, 8), 256, 0, stream>>>(img, imgT);
  k_prep<<<512, 256, 0, stream>>>(te, roi, ln_off_g, ln_off_b, w_off, off_bias,
                                  ln_pg_g, ln_pg_b, w_pg1, b_pg1, tb16, meta_i, meta_w);
  k_sample<<<512, 256, 0, stream>>>(imgT, meta_i, meta_w, Sbuf);
  k_wt<<<7680, 256, 0, stream>>>(w_out, w_outT, w_qkv, w_qkvT, w_proj, w_projT,
                                 w_fc1, w_fc1T, w_fc2, w_fc2T);
  k_pg2_mfma<<<dim3(1045, 2), 256, 0, stream>>>(tb16, w_pg2, b_pg2, pchunk);
  k_cmT<<<dim3(16, 512), 256, 0, stream>>>(pchunk, pcmT);
  k_mix3<<<dim3(512, 2), 256, 0, stream>>>(pchunk, pcmT, Sbuf, m_beta, s_beta, h2);

  k_gemm_bt<<<dim3(8, 8, 8), 256, 0, stream>>>(h2, w_outT, part, 512, 512, 9216);
  k_epi<<<1024, 256, 0, stream>>>(part, 8, 512 * 512, 512, b_out, te, 0, x1, nullptr);

  k_ln<<<512, 256, 0, stream>>>(x1, ln1_g, ln1_b, ln1buf);
  k_gemm_bt<<<dim3(24, 8, 2), 256, 0, stream>>>(ln1buf, w_qkvT, part, 512, 1536, 512);
  k_epi<<<3072, 256, 0, stream>>>(part, 2, 512 * 1536, 1536, b_qkv, nullptr, 0, qkvf, nullptr);
  k_attn<<<64, 256, 0, stream>>>(qkvf, obuf);
  k_gemm_bt<<<dim3(8, 8, 4), 256, 0, stream>>>(obuf, w_projT, part, 512, 512, 512);
  k_epi<<<1024, 256, 0, stream>>>(part, 4, 512 * 512, 512, b_proj, x1, 0, xa, nullptr);

  k_ln<<<512, 256, 0, stream>>>(xa, ln2_g, ln2_b, ln2buf);
  k_gemm_bt<<<dim3(32, 8, 2), 256, 0, stream>>>(ln2buf, w_fc1T, part, 512, 2048, 512);
  k_epi<<<4096, 256, 0, stream>>>(part, 2, 512 * 2048, 2048, b_fc1, nullptr, 1, nullptr, hfc);
  k_gemm_bt<<<dim3(8, 8, 4), 256, 0, stream>>>(hfc, w_fc2T, part, 512, 512, 2048);
  k_epi<<<1024, 256, 0, stream>>>(part, 4, 512 * 512, 512, b_fc2, xa, 0, (float*)d_out, nullptr);
}